// Round 1
// baseline (110.920 us; speedup 1.0000x reference)
//
#include <hip/hip_runtime.h>
#include <stdint.h>

constexpr int L_LEVELS = 16;
constexpr int T_SIZE   = 16384;
constexpr int N_PTS    = 262144;

typedef _Float16 h2 __attribute__((ext_vector_type(2)));
typedef _Float16 h8 __attribute__((ext_vector_type(8)));

// Byte-offset-scaled hash constants: prime*4 mod 2^32, mask (T-1)*4.
constexpr uint32_t P1_4 = 2654435761u * 4u;
constexpr uint32_t P2_4 = 805459861u * 4u;
constexpr uint32_t M4   = (T_SIZE - 1) * 4u;   // 65532

__device__ __forceinline__ h2 lerp2(h2 a, h2 b, h2 t) {
    return a + t * (b - a);                     // v_pk_sub + v_pk_fma
}

// ---------------------------------------------------------------------------
// Kernel 0: convert f32 tables (L,T,2) -> fp16 h2 tables in ws (1 MiB).
// One-time: 2 MB read, 1 MB write. Replaces 1024 in-block f32 stagings+cvt.
// ---------------------------------------------------------------------------
__global__ __launch_bounds__(256) void cvt_tables(
    const float* __restrict__ emb, h2* __restrict__ tbl)
{
    const int i = blockIdx.x * 256 + threadIdx.x;        // 4 entries per thread
    const float4* __restrict__ s = reinterpret_cast<const float4*>(emb);
    float4 a = s[2 * i];
    float4 b = s[2 * i + 1];
    h8 w = { (_Float16)a.x, (_Float16)a.y, (_Float16)a.z, (_Float16)a.w,
             (_Float16)b.x, (_Float16)b.y, (_Float16)b.z, (_Float16)b.w };
    reinterpret_cast<h8*>(tbl)[i] = w;                   // 16 B store
}

// ---------------------------------------------------------------------------
// Kernel 1: fused all-level hash encode.
// 256 blocks x 1024 threads = 1 point/thread, all 16 levels per thread.
// LDS: double-buffered fp16 table (2 x 64 KB = 128 KB -> 1 block/CU,
// 16 waves/CU). Per level: prefetch next table into regs (hidden under
// compute), gather 8 corners (gray-code XOR chain), packed-fp16 lerp tree,
// ds_write next table, ONE barrier. Output: each thread writes its point's
// full (L*F)=32-float row as 8 contiguous dwordx4 -> no transpose kernel,
// no 16 MB ws intermediate.
// ---------------------------------------------------------------------------
__global__ __launch_bounds__(1024, 4) void hash_encode_fused(
    const float* __restrict__ x,
    const h2*    __restrict__ tbl,    // (L, T) fp16 feature pairs
    float4*      __restrict__ out)    // (N, 8 float4) = (N, 32 floats)
{
    __shared__ h2 tab[2][T_SIZE];     // 2 x 64 KB

    const int t = threadIdx.x;        // 0..1023
    const int n = blockIdx.x * 1024 + t;

    // Point coords: read once, kept in VGPRs for all 16 levels.
    const float x0 = x[3 * n + 0];
    const float x1 = x[3 * n + 1];
    const float x2 = x[3 * n + 2];

    // Prologue: stage level-0 table (64 KB = 1024 threads x 1 h8 x 4 rounds).
    {
        const h8* __restrict__ s = reinterpret_cast<const h8*>(tbl);
        h8* __restrict__ d = reinterpret_cast<h8*>(tab[0]);
#pragma unroll
        for (int r = 0; r < 4; ++r) d[r * 1024 + t] = s[r * 1024 + t];
    }
    __syncthreads();

    h2 res[L_LEVELS];

#pragma unroll
    for (int l = 0; l < L_LEVELS; ++l) {
        // Issue next-level staging loads first: global_load latency hides
        // under this level's gathers + lerps. (h8 = dwordx4 each.)
        h8 stg0, stg1, stg2, stg3;
        if (l < L_LEVELS - 1) {
            const h8* __restrict__ s =
                reinterpret_cast<const h8*>(tbl + (size_t)(l + 1) * T_SIZE);
            stg0 = s[0 * 1024 + t];
            stg1 = s[1 * 1024 + t];
            stg2 = s[2 * 1024 + t];
            stg3 = s[3 * 1024 + t];
        }

        // N_l = 16 * 2^(5l/16); constant-folded per unrolled level.
        const float Nl = 16.0f * exp2f((float)l * 0.3125f);
        const char* __restrict__ tb =
            reinterpret_cast<const char*>(tab[l & 1]);

        const float u0 = x0 * Nl, u1 = x1 * Nl, u2 = x2 * Nl;
        // u >= 0: df = u - floor(u); exact-integer case gives df=0 which
        // zeroes the (possibly wrong-slot) hi-corner lerp term -> correct.
        const float fl0 = floorf(u0), fl1 = floorf(u1), fl2 = floorf(u2);
        const float df0 = u0 - fl0, df1 = u1 - fl1, df2 = u2 - fl2;

        // Byte-offset hash products for the lo corner (prime*4, wrapping).
        const uint32_t q0 = ((uint32_t)(int32_t)fl0) << 2;       // prime 1
        const uint32_t q1 = ((uint32_t)(int32_t)fl1) * P1_4;
        const uint32_t q2 = ((uint32_t)(int32_t)fl2) * P2_4;
        // Masked XOR deltas per dim ((a^b)&M4; <<2 / mul distribute mod 2^32)
        const uint32_t d0 = (q0 ^ (q0 + 4u))   & M4;
        const uint32_t d1 = (q1 ^ (q1 + P1_4)) & M4;
        const uint32_t d2 = (q2 ^ (q2 + P2_4)) & M4;

        uint32_t off = (q0 ^ q1 ^ q2) & M4;     // corner 000 byte offset

        // Gray-code gather order: one XOR per subsequent corner address.
        constexpr int gray[8] = {0, 1, 3, 2, 6, 7, 5, 4};
        h2 f[8];
#pragma unroll
        for (int j = 0; j < 8; ++j) {
            f[gray[j]] = *reinterpret_cast<const h2*>(tb + off);  // ds_read_b32
            if (j < 7) {
                const int tog = gray[j] ^ gray[j + 1];            // 4,2 or 1
                off ^= (tog == 4) ? d0 : (tog == 2) ? d1 : d2;
            }
        }

        // Packed-fp16 trilinear lerp tree (both features per register).
        const _Float16 h0 = (_Float16)df0, h1 = (_Float16)df1, hv2 = (_Float16)df2;
        const h2 t0 = {h0, h0}, t1 = {h1, h1}, t2 = {hv2, hv2};
        h2 e0 = lerp2(f[0], f[1], t2);
        h2 e1 = lerp2(f[2], f[3], t2);
        h2 e2 = lerp2(f[4], f[5], t2);
        h2 e3 = lerp2(f[6], f[7], t2);
        h2 g0 = lerp2(e0, e1, t1);
        h2 g1 = lerp2(e2, e3, t1);
        res[l] = lerp2(g0, g1, t0);

        // Write next-level table into the other LDS buffer. Safe without a
        // preceding barrier: that buffer was last READ during level l-1,
        // and the end-of-(l-1) barrier already separates those reads from
        // these writes. The single end-of-level barrier makes the writes
        // visible before level l+1's gathers.
        if (l < L_LEVELS - 1) {
            h8* __restrict__ d = reinterpret_cast<h8*>(tab[(l + 1) & 1]);
            d[0 * 1024 + t] = stg0;
            d[1 * 1024 + t] = stg1;
            d[2 * 1024 + t] = stg2;
            d[3 * 1024 + t] = stg3;
            __syncthreads();
        }
    }

    // Epilogue: 128 B contiguous per point -> 8 dwordx4 stores, lines get
    // fully written in L2 (no write amplification), no transpose needed.
    float4* __restrict__ o = out + (size_t)n * 8;
#pragma unroll
    for (int i = 0; i < 8; ++i)
        o[i] = make_float4((float)res[2 * i].x,     (float)res[2 * i].y,
                           (float)res[2 * i + 1].x, (float)res[2 * i + 1].y);
}

// ---------------------------------------------------------------------------
// Fallback (ws too small): previous per-(level,chunk) kernel, direct scatter.
// ---------------------------------------------------------------------------
__global__ __launch_bounds__(512, 4) void hash_encode_lds_direct(
    const float* __restrict__ x,
    const float* __restrict__ emb,
    float2* __restrict__ dst)
{
    __shared__ h2 tab[T_SIZE];                  // 64 KB

    const int l     = blockIdx.x & (L_LEVELS - 1);
    const int chunk = blockIdx.x >> 4;
    const int t     = threadIdx.x;
    const int n0    = chunk * 4096 + t * 8;

    {
        const float4* __restrict__ src =
            reinterpret_cast<const float4*>(emb + (size_t)l * T_SIZE * 2);
        h8* __restrict__ d8 = reinterpret_cast<h8*>(tab);
#pragma unroll
        for (int it = 0; it < 8; ++it) {
            const int i = it * 512 + t;
            float4 a = src[2 * i];
            float4 b = src[2 * i + 1];
            h8 w = { (_Float16)a.x, (_Float16)a.y, (_Float16)a.z, (_Float16)a.w,
                     (_Float16)b.x, (_Float16)b.y, (_Float16)b.z, (_Float16)b.w };
            d8[i] = w;
        }
    }

    union { float4 q[6]; float f[24]; } xs;
    {
        const float4* __restrict__ xv =
            reinterpret_cast<const float4*>(x + (size_t)n0 * 3);
#pragma unroll
        for (int i = 0; i < 6; ++i) xs.q[i] = xv[i];
    }

    __syncthreads();

    const float Nl = 16.0f * exp2f((float)l * 0.3125f);
    const char* __restrict__ tb = reinterpret_cast<const char*>(tab);

#pragma unroll
    for (int p = 0; p < 8; ++p) {
        const float u0 = xs.f[3 * p + 0] * Nl;
        const float u1 = xs.f[3 * p + 1] * Nl;
        const float u2 = xs.f[3 * p + 2] * Nl;

        const float fl0 = floorf(u0), fl1 = floorf(u1), fl2 = floorf(u2);
        const float df0 = u0 - fl0, df1 = u1 - fl1, df2 = u2 - fl2;

        const uint32_t q0 = ((uint32_t)(int32_t)fl0) << 2;
        const uint32_t q1 = ((uint32_t)(int32_t)fl1) * P1_4;
        const uint32_t q2 = ((uint32_t)(int32_t)fl2) * P2_4;
        const uint32_t d0 = (q0 ^ (q0 + 4u))   & M4;
        const uint32_t d1 = (q1 ^ (q1 + P1_4)) & M4;
        const uint32_t d2 = (q2 ^ (q2 + P2_4)) & M4;

        uint32_t off = (q0 ^ q1 ^ q2) & M4;

        constexpr int gray[8] = {0, 1, 3, 2, 6, 7, 5, 4};
        h2 f[8];
#pragma unroll
        for (int j = 0; j < 8; ++j) {
            f[gray[j]] = *reinterpret_cast<const h2*>(tb + off);
            if (j < 7) {
                const int tog = gray[j] ^ gray[j + 1];
                off ^= (tog == 4) ? d0 : (tog == 2) ? d1 : d2;
            }
        }

        const _Float16 h0 = (_Float16)df0, h1 = (_Float16)df1, hv2 = (_Float16)df2;
        const h2 t0 = {h0, h0}, t1 = {h1, h1}, t2 = {hv2, hv2};
        h2 e0 = lerp2(f[0], f[1], t2);
        h2 e1 = lerp2(f[2], f[3], t2);
        h2 e2 = lerp2(f[4], f[5], t2);
        h2 e3 = lerp2(f[6], f[7], t2);
        h2 g0 = lerp2(e0, e1, t1);
        h2 g1 = lerp2(e2, e3, t1);
        dst[(size_t)(n0 + p) * L_LEVELS + l] =
            make_float2((float)g0.x + (float)t0.x * ((float)g1.x - (float)g0.x),
                        (float)g0.y + (float)t0.y * ((float)g1.y - (float)g0.y));
    }
}

extern "C" void kernel_launch(void* const* d_in, const int* in_sizes, int n_in,
                              void* d_out, int out_size, void* d_ws, size_t ws_size,
                              hipStream_t stream) {
    const float* x   = (const float*)d_in[0];
    const float* emb = (const float*)d_in[1];

    const size_t tbl_bytes = (size_t)L_LEVELS * T_SIZE * sizeof(h2); // 1 MiB

    if (ws_size >= tbl_bytes) {
        cvt_tables<<<256, 256, 0, stream>>>(emb, (h2*)d_ws);
        hash_encode_fused<<<256, 1024, 0, stream>>>(x, (const h2*)d_ws,
                                                    (float4*)d_out);
    } else {
        hash_encode_lds_direct<<<1024, 512, 0, stream>>>(x, emb,
                                                         (float2*)d_out);
    }
}

// Round 2
// 94.364 us; speedup vs baseline: 1.1754x; 1.1754x over previous
//
#include <hip/hip_runtime.h>
#include <stdint.h>

constexpr int L_LEVELS = 16;
constexpr int T_SIZE   = 16384;
constexpr int N_PTS    = 262144;

typedef _Float16 h2 __attribute__((ext_vector_type(2)));
typedef _Float16 h4 __attribute__((ext_vector_type(4)));
typedef _Float16 h8 __attribute__((ext_vector_type(8)));

// Byte-offset-scaled hash constants: prime*4 mod 2^32, mask (T-1)*4.
constexpr uint32_t P1_4 = 2654435761u * 4u;
constexpr uint32_t P2_4 = 805459861u * 4u;
constexpr uint32_t M4   = (T_SIZE - 1) * 4u;   // 65532

__device__ __forceinline__ h2 lerp2(h2 a, h2 b, h2 t) {
    return a + t * (b - a);                     // v_pk_sub + v_pk_fma
}

// ---------------------------------------------------------------------------
// Kernel 0: convert f32 tables (L,T,2) -> fp16 h2 tables in ws (1 MiB).
// ---------------------------------------------------------------------------
__global__ __launch_bounds__(256) void cvt_tables(
    const float* __restrict__ emb, h2* __restrict__ tbl)
{
    const int i = blockIdx.x * 256 + threadIdx.x;        // 4 entries per thread
    const float4* __restrict__ s = reinterpret_cast<const float4*>(emb);
    float4 a = s[2 * i];
    float4 b = s[2 * i + 1];
    h8 w = { (_Float16)a.x, (_Float16)a.y, (_Float16)a.z, (_Float16)a.w,
             (_Float16)b.x, (_Float16)b.y, (_Float16)b.z, (_Float16)b.w };
    reinterpret_cast<h8*>(tbl)[i] = w;                   // 16 B store
}

// ---------------------------------------------------------------------------
// Kernel 1: fused all-level hash encode.
// 256 blocks x 1024 threads = 1 point/thread, all 16 levels.
// LDS: double-buffered fp16 table (2 x 64 KB). Per level: prefetch next
// table into regs (hidden under gathers+lerps), gather 8 corners, packed
// fp16 lerp tree, ds_write next table, ONE barrier.
// Epilogue fix (this round): results are transposed through LDS (reusing
// the dead table buffers, 80 B-padded rows for ~conflict-free DS access)
// so global stores are LANE-contiguous full-line float4 stores. The old
// per-thread 8x16B @128B-stride stores caused partial-line evictions:
// WRITE_SIZE 74.7 MB vs 32 MB output + 22 MB write-allocate refetches.
// ---------------------------------------------------------------------------
__global__ __launch_bounds__(1024, 4) void hash_encode_fused(
    const float* __restrict__ x,
    const h2*    __restrict__ tbl,    // (L, T) fp16 feature pairs
    float4*      __restrict__ out)    // (N, 8 float4) = (N, 32 floats)
{
    __shared__ union {
        h2 tab[2][T_SIZE];            // 2 x 64 KB, level double-buffer
        h2 tr[1024][20];              // 80 KB transpose buffer (padded row:
                                      // 20 h2 = 80 B -> DS banks spread)
    } sm;

    const int t = threadIdx.x;        // 0..1023
    const int n = blockIdx.x * 1024 + t;

    // Per-block rotation of staging order: de-hotspots L2 (all blocks
    // otherwise read identical table addresses in lockstep). Same index
    // permutation on src and dst keeps LDS contents identical.
    const int rot = (blockIdx.x << 4) & 4095;

    // Point coords: read once, kept in VGPRs for all 16 levels.
    const float x0 = x[3 * n + 0];
    const float x1 = x[3 * n + 1];
    const float x2 = x[3 * n + 2];

    // Prologue: stage level-0 table (64 KB = 4096 h8, 4 per thread).
    {
        const h8* __restrict__ s = reinterpret_cast<const h8*>(tbl);
        h8* __restrict__ d = reinterpret_cast<h8*>(sm.tab[0]);
#pragma unroll
        for (int r = 0; r < 4; ++r) {
            const int j = (r * 1024 + t + rot) & 4095;
            d[j] = s[j];
        }
    }
    __syncthreads();

    union { h2 r[L_LEVELS]; h8 q[4]; } res;

#pragma unroll
    for (int l = 0; l < L_LEVELS; ++l) {
        // Issue next-level staging loads first: L2 latency hides under
        // this level's gathers + lerps. (h8 = dwordx4 each.)
        h8 stg0, stg1, stg2, stg3;
        int j0 = 0, j1 = 0, j2 = 0, j3 = 0;
        if (l < L_LEVELS - 1) {
            const h8* __restrict__ s =
                reinterpret_cast<const h8*>(tbl + (size_t)(l + 1) * T_SIZE);
            j0 = (0 * 1024 + t + rot) & 4095;
            j1 = (1 * 1024 + t + rot) & 4095;
            j2 = (2 * 1024 + t + rot) & 4095;
            j3 = (3 * 1024 + t + rot) & 4095;
            stg0 = s[j0];
            stg1 = s[j1];
            stg2 = s[j2];
            stg3 = s[j3];
        }

        // N_l = 16 * 2^(5l/16); constant-folded per unrolled level.
        const float Nl = 16.0f * exp2f((float)l * 0.3125f);
        const char* __restrict__ tb =
            reinterpret_cast<const char*>(sm.tab[l & 1]);

        const float u0 = x0 * Nl, u1 = x1 * Nl, u2 = x2 * Nl;
        // u >= 0: df = u - floor(u); exact-integer case gives df=0 which
        // zeroes the (possibly wrong-slot) hi-corner lerp term -> correct.
        const float fl0 = floorf(u0), fl1 = floorf(u1), fl2 = floorf(u2);
        const float df0 = u0 - fl0, df1 = u1 - fl1, df2 = u2 - fl2;

        // Byte-offset hash products for the lo corner (prime*4, wrapping).
        const uint32_t q0 = ((uint32_t)(int32_t)fl0) << 2;       // prime 1
        const uint32_t q1 = ((uint32_t)(int32_t)fl1) * P1_4;
        const uint32_t q2 = ((uint32_t)(int32_t)fl2) * P2_4;
        // Masked XOR deltas per dim ((a^b)&M4; <<2 / mul distribute mod 2^32)
        const uint32_t d0 = (q0 ^ (q0 + 4u))   & M4;
        const uint32_t d1 = (q1 ^ (q1 + P1_4)) & M4;
        const uint32_t d2 = (q2 ^ (q2 + P2_4)) & M4;

        uint32_t off = (q0 ^ q1 ^ q2) & M4;     // corner 000 byte offset

        // Gray-code gather order: one XOR per subsequent corner address.
        constexpr int gray[8] = {0, 1, 3, 2, 6, 7, 5, 4};
        h2 f[8];
#pragma unroll
        for (int j = 0; j < 8; ++j) {
            f[gray[j]] = *reinterpret_cast<const h2*>(tb + off);  // ds_read_b32
            if (j < 7) {
                const int tog = gray[j] ^ gray[j + 1];            // 4,2 or 1
                off ^= (tog == 4) ? d0 : (tog == 2) ? d1 : d2;
            }
        }

        // Packed-fp16 trilinear lerp tree (both features per register).
        const _Float16 h0 = (_Float16)df0, h1 = (_Float16)df1, hv2 = (_Float16)df2;
        const h2 t0 = {h0, h0}, t1 = {h1, h1}, t2 = {hv2, hv2};
        h2 e0 = lerp2(f[0], f[1], t2);
        h2 e1 = lerp2(f[2], f[3], t2);
        h2 e2 = lerp2(f[4], f[5], t2);
        h2 e3 = lerp2(f[6], f[7], t2);
        h2 g0 = lerp2(e0, e1, t1);
        h2 g1 = lerp2(e2, e3, t1);
        res.r[l] = lerp2(g0, g1, t0);

        // Write next-level table into the other LDS buffer. Safe without a
        // preceding barrier: that buffer was last READ during level l-1,
        // separated by the end-of-(l-1) barrier. The single end-of-level
        // barrier makes these writes visible before level l+1's gathers.
        if (l < L_LEVELS - 1) {
            h8* __restrict__ d = reinterpret_cast<h8*>(sm.tab[(l + 1) & 1]);
            d[j0] = stg0;
            d[j1] = stg1;
            d[j2] = stg2;
            d[j3] = stg3;
            __syncthreads();
        }
    }

    // ---- Epilogue: LDS transpose -> lane-contiguous full-line stores ----
    // tr overlaps tab[1] (still being gathered above), so one barrier first.
    __syncthreads();
#pragma unroll
    for (int g = 0; g < 4; ++g)          // 4 x ds_write_b128, 80 B row stride
        *reinterpret_cast<h8*>(&sm.tr[t][4 * g]) = res.q[g];
    __syncthreads();

    // Thread t, iter i handles flat block-local float4 #(i*1024+t):
    // point p = i*128 + t/8, levels 2*(t&7) and 2*(t&7)+1.
    float4* __restrict__ o = out + (size_t)blockIdx.x * 8192;
#pragma unroll
    for (int i = 0; i < 8; ++i) {
        const int p  = i * 128 + (t >> 3);
        const int l0 = 2 * (t & 7);
        h4 v = *reinterpret_cast<const h4*>(&sm.tr[p][l0]);   // ds_read_b64
        o[i * 1024 + t] = make_float4((float)v.x, (float)v.y,
                                      (float)v.z, (float)v.w); // 1 KB/instr
    }
}

// ---------------------------------------------------------------------------
// Fallback (ws too small): per-(level,chunk) kernel, direct scatter.
// ---------------------------------------------------------------------------
__global__ __launch_bounds__(512, 4) void hash_encode_lds_direct(
    const float* __restrict__ x,
    const float* __restrict__ emb,
    float2* __restrict__ dst)
{
    __shared__ h2 tab[T_SIZE];                  // 64 KB

    const int l     = blockIdx.x & (L_LEVELS - 1);
    const int chunk = blockIdx.x >> 4;
    const int t     = threadIdx.x;
    const int n0    = chunk * 4096 + t * 8;

    {
        const float4* __restrict__ src =
            reinterpret_cast<const float4*>(emb + (size_t)l * T_SIZE * 2);
        h8* __restrict__ d8 = reinterpret_cast<h8*>(tab);
#pragma unroll
        for (int it = 0; it < 8; ++it) {
            const int i = it * 512 + t;
            float4 a = src[2 * i];
            float4 b = src[2 * i + 1];
            h8 w = { (_Float16)a.x, (_Float16)a.y, (_Float16)a.z, (_Float16)a.w,
                     (_Float16)b.x, (_Float16)b.y, (_Float16)b.z, (_Float16)b.w };
            d8[i] = w;
        }
    }

    union { float4 q[6]; float f[24]; } xs;
    {
        const float4* __restrict__ xv =
            reinterpret_cast<const float4*>(x + (size_t)n0 * 3);
#pragma unroll
        for (int i = 0; i < 6; ++i) xs.q[i] = xv[i];
    }

    __syncthreads();

    const float Nl = 16.0f * exp2f((float)l * 0.3125f);
    const char* __restrict__ tb = reinterpret_cast<const char*>(tab);

#pragma unroll
    for (int p = 0; p < 8; ++p) {
        const float u0 = xs.f[3 * p + 0] * Nl;
        const float u1 = xs.f[3 * p + 1] * Nl;
        const float u2 = xs.f[3 * p + 2] * Nl;

        const float fl0 = floorf(u0), fl1 = floorf(u1), fl2 = floorf(u2);
        const float df0 = u0 - fl0, df1 = u1 - fl1, df2 = u2 - fl2;

        const uint32_t q0 = ((uint32_t)(int32_t)fl0) << 2;
        const uint32_t q1 = ((uint32_t)(int32_t)fl1) * P1_4;
        const uint32_t q2 = ((uint32_t)(int32_t)fl2) * P2_4;
        const uint32_t d0 = (q0 ^ (q0 + 4u))   & M4;
        const uint32_t d1 = (q1 ^ (q1 + P1_4)) & M4;
        const uint32_t d2 = (q2 ^ (q2 + P2_4)) & M4;

        uint32_t off = (q0 ^ q1 ^ q2) & M4;

        constexpr int gray[8] = {0, 1, 3, 2, 6, 7, 5, 4};
        h2 f[8];
#pragma unroll
        for (int j = 0; j < 8; ++j) {
            f[gray[j]] = *reinterpret_cast<const h2*>(tb + off);
            if (j < 7) {
                const int tog = gray[j] ^ gray[j + 1];
                off ^= (tog == 4) ? d0 : (tog == 2) ? d1 : d2;
            }
        }

        const _Float16 h0 = (_Float16)df0, h1 = (_Float16)df1, hv2 = (_Float16)df2;
        const h2 t0 = {h0, h0}, t1 = {h1, h1}, t2 = {hv2, hv2};
        h2 e0 = lerp2(f[0], f[1], t2);
        h2 e1 = lerp2(f[2], f[3], t2);
        h2 e2 = lerp2(f[4], f[5], t2);
        h2 e3 = lerp2(f[6], f[7], t2);
        h2 g0 = lerp2(e0, e1, t1);
        h2 g1 = lerp2(e2, e3, t1);
        h2 r  = lerp2(g0, g1, t0);
        dst[(size_t)(n0 + p) * L_LEVELS + l] =
            make_float2((float)r.x, (float)r.y);
    }
}

extern "C" void kernel_launch(void* const* d_in, const int* in_sizes, int n_in,
                              void* d_out, int out_size, void* d_ws, size_t ws_size,
                              hipStream_t stream) {
    const float* x   = (const float*)d_in[0];
    const float* emb = (const float*)d_in[1];

    const size_t tbl_bytes = (size_t)L_LEVELS * T_SIZE * sizeof(h2); // 1 MiB

    if (ws_size >= tbl_bytes) {
        cvt_tables<<<256, 256, 0, stream>>>(emb, (h2*)d_ws);
        hash_encode_fused<<<256, 1024, 0, stream>>>(x, (const h2*)d_ws,
                                                    (float4*)d_out);
    } else {
        hash_encode_lds_direct<<<1024, 512, 0, stream>>>(x, emb,
                                                         (float2*)d_out);
    }
}